// Round 16
// baseline (167.166 us; speedup 1.0000x reference)
//
#include <hip/hip_runtime.h>
#include <hip/hip_cooperative_groups.h>

// ConditionalPreactivation: out = Z @ Wflat + bf @ bvec,
//   Z[b, k*512+i] = bf[b,k] * a[b,i],  a = lrelu(LN(x)),  bf = basis(c).
// Round 16 = Round 15 with the reduce FUSED into the gemm via cooperative
// launch (grid.sync after partial stores; each block reduces its own 4 KB
// output chunk).  Runtime fallback to the proven non-fused pair if the
// cooperative launch is rejected.  Gemm schedule byte-identical to R12/R15:
// 128x128/BK64 deep pipeline, 2-deep dbuf, counted vmcnt(8), raw barriers,
// T2 both-sides swizzle, setprio, 2 blocks/CU, NSPLIT=4, f16 partials,
// bvec folded in epilogue.
// B=4096, DIN=512, DOUT=512, DC=64, K=16, DB=256.

#define LRELU(v) ((v) >= 0.f ? (v) : 0.01f * (v))

typedef _Float16 f16x8 __attribute__((ext_vector_type(8)));
typedef float f32x4 __attribute__((ext_vector_type(4)));

#define GL16(gp, lp) __builtin_amdgcn_global_load_lds(                      \
    (const __attribute__((address_space(1))) void*)(gp),                    \
    (__attribute__((address_space(3))) void*)(lp), 16, 0, 0)

#define MFMA16(a, b, c) __builtin_amdgcn_mfma_f32_16x16x32_f16((a), (b), (c), 0, 0, 0)

// ---------------------------------------------------------------------------
// Fused prep: blocks [0,512)      basis functions -> bf f32  (8 rows/block)
//             blocks [512,1536)   W f32 -> Wt f16 transposed [o][k*512+i]
//             blocks [1536,2560)  LayerNorm+lrelu -> a f16
// [UNCHANGED from round 15]
// ---------------------------------------------------------------------------
__global__ __launch_bounds__(256) void prep_kernel(
    const float* __restrict__ x, const float* __restrict__ gam,
    const float* __restrict__ bet, _Float16* __restrict__ a,
    const float* __restrict__ c, const float* __restrict__ w1,
    const float* __restrict__ b1, const float* __restrict__ wr,
    const float* __restrict__ br, const float* __restrict__ w2,
    const float* __restrict__ b2, float* __restrict__ bfo,
    const float* __restrict__ W, _Float16* __restrict__ Wt)
{
    __shared__ __align__(16) char smem[18432];
    int tid = threadIdx.x;
    int blk = blockIdx.x;

    if (blk < 512) {
        float* c_l  = (float*)smem;             // 8*64  = 2 KB
        float* lr_l = (float*)(smem + 2048);    // 8*256 = 8 KB
        float* h_l  = (float*)(smem + 10240);   // 8*256 = 8 KB
        int b0 = blk * 8;

        for (int i = tid; i < 8 * 64; i += 256) c_l[i] = c[(size_t)b0 * 64 + i];

        float w1c[64];
#pragma unroll
        for (int u = 0; u < 64; ++u) w1c[u] = w1[u * 256 + tid];
        float b1s = b1[tid];
        __syncthreads();

        float h1[8];
#pragma unroll
        for (int r = 0; r < 8; ++r) h1[r] = b1s;
#pragma unroll
        for (int j4 = 0; j4 < 16; ++j4) {
#pragma unroll
            for (int r = 0; r < 8; ++r) {
                float4 cv = *(const float4*)&c_l[r * 64 + j4 * 4];
                h1[r] += cv.x * w1c[j4 * 4 + 0] + cv.y * w1c[j4 * 4 + 1] +
                         cv.z * w1c[j4 * 4 + 2] + cv.w * w1c[j4 * 4 + 3];
            }
        }
#pragma unroll
        for (int r = 0; r < 8; ++r) lr_l[r * 256 + tid] = LRELU(h1[r]);
        __syncthreads();

        float brv = br[tid];
        float h2[8];
#pragma unroll
        for (int r = 0; r < 8; ++r) h2[r] = h1[r] + brv;

#pragma unroll 1
        for (int jc = 0; jc < 4; ++jc) {
            float w8[64];
#pragma unroll
            for (int u = 0; u < 64; ++u) w8[u] = wr[(jc * 64 + u) * 256 + tid];
#pragma unroll
            for (int j4 = 0; j4 < 16; ++j4) {
#pragma unroll
                for (int r = 0; r < 8; ++r) {
                    float4 lv = *(const float4*)&lr_l[r * 256 + jc * 64 + j4 * 4];
                    h2[r] += lv.x * w8[j4 * 4 + 0] + lv.y * w8[j4 * 4 + 1] +
                             lv.z * w8[j4 * 4 + 2] + lv.w * w8[j4 * 4 + 3];
                }
            }
        }
#pragma unroll
        for (int r = 0; r < 8; ++r) h_l[r * 256 + tid] = LRELU(h2[r]);
        __syncthreads();

        {
            int p    = tid >> 6;
            int lane = tid & 63;
            int k    = lane & 15;
            int seg  = lane >> 4;
            int r0   = 2 * p, r1 = 2 * p + 1;
            float acc0 = 0.f, acc1 = 0.f;
#pragma unroll 1
            for (int ch = 0; ch < 2; ++ch) {
                int qb = seg * 64 + ch * 32;
                float wv[32];
#pragma unroll
                for (int u = 0; u < 32; ++u) wv[u] = w2[(qb + u) * 16 + k];
#pragma unroll
                for (int q4 = 0; q4 < 8; ++q4) {
                    float4 h0 = *(const float4*)&h_l[r0 * 256 + qb + q4 * 4];
                    float4 h1v = *(const float4*)&h_l[r1 * 256 + qb + q4 * 4];
                    float wa = wv[q4 * 4 + 0], wb = wv[q4 * 4 + 1];
                    float wc = wv[q4 * 4 + 2], wd = wv[q4 * 4 + 3];
                    acc0 += h0.x * wa + h0.y * wb + h0.z * wc + h0.w * wd;
                    acc1 += h1v.x * wa + h1v.y * wb + h1v.z * wc + h1v.w * wd;
                }
            }
            acc0 += __shfl_xor(acc0, 16); acc0 += __shfl_xor(acc0, 32);
            acc1 += __shfl_xor(acc1, 16); acc1 += __shfl_xor(acc1, 32);
            if (lane < 16) {
                float b2v = b2[k];
                bfo[(size_t)(b0 + r0) * 16 + k] = acc0 + b2v;
                bfo[(size_t)(b0 + r1) * 16 + k] = acc1 + b2v;
            }
        }

    } else if (blk < 1536) {
        float* t = (float*)smem;  // 64*65*4 = 16.25 KB
        int bid = blk - 512;
        int k  = bid >> 6;
        int it = (bid >> 3) & 7;
        int ot = bid & 7;
        int i0 = it * 64, o0 = ot * 64;

        int rr = tid >> 4, c4 = (tid & 15) * 4;
#pragma unroll
        for (int p = 0; p < 4; ++p) {
            int r = p * 16 + rr;
            float4 v = *(const float4*)&W[((size_t)(k * 512 + i0 + r)) * 512 + o0 + c4];
            t[r * 65 + c4 + 0] = v.x;
            t[r * 65 + c4 + 1] = v.y;
            t[r * 65 + c4 + 2] = v.z;
            t[r * 65 + c4 + 3] = v.w;
        }
        __syncthreads();

        int ol = tid >> 2, c0 = (tid & 3) * 16;
        _Float16 hb[16] __attribute__((aligned(16)));
#pragma unroll
        for (int u = 0; u < 16; ++u) hb[u] = (_Float16)t[(c0 + u) * 65 + ol];
        _Float16* dst = &Wt[(size_t)(o0 + ol) * 8192 + k * 512 + i0 + c0];
        *(float4*)dst       = *(const float4*)&hb[0];
        *(float4*)(dst + 8) = *(const float4*)&hb[8];

    } else {
        int lane = tid & 63;
        int row  = (blk - 1536) * 4 + (tid >> 6);
        const float* xr = x + (size_t)row * 512 + lane * 8;
        float4 v0 = *(const float4*)xr;
        float4 v1 = *(const float4*)(xr + 4);

        float s = v0.x + v0.y + v0.z + v0.w + v1.x + v1.y + v1.z + v1.w;
#pragma unroll
        for (int m = 1; m < 64; m <<= 1) s += __shfl_xor(s, m);
        float mean = s * (1.f / 512.f);

        float d, s2 = 0.f;
        d = v0.x - mean; s2 += d * d;
        d = v0.y - mean; s2 += d * d;
        d = v0.z - mean; s2 += d * d;
        d = v0.w - mean; s2 += d * d;
        d = v1.x - mean; s2 += d * d;
        d = v1.y - mean; s2 += d * d;
        d = v1.z - mean; s2 += d * d;
        d = v1.w - mean; s2 += d * d;
#pragma unroll
        for (int m = 1; m < 64; m <<= 1) s2 += __shfl_xor(s2, m);
        float rstd = rsqrtf(s2 * (1.f / 512.f) + 1e-5f);

        float4 g0 = *(const float4*)&gam[lane * 8];
        float4 g1 = *(const float4*)&gam[lane * 8 + 4];
        float4 b0 = *(const float4*)&bet[lane * 8];
        float4 b1v = *(const float4*)&bet[lane * 8 + 4];

        _Float16 o8[8] __attribute__((aligned(16)));
        float y;
        y = (v0.x - mean) * rstd * g0.x + b0.x;  y = LRELU(y); o8[0] = (_Float16)y;
        y = (v0.y - mean) * rstd * g0.y + b0.y;  y = LRELU(y); o8[1] = (_Float16)y;
        y = (v0.z - mean) * rstd * g0.z + b0.z;  y = LRELU(y); o8[2] = (_Float16)y;
        y = (v0.w - mean) * rstd * g0.w + b0.w;  y = LRELU(y); o8[3] = (_Float16)y;
        y = (v1.x - mean) * rstd * g1.x + b1v.x; y = LRELU(y); o8[4] = (_Float16)y;
        y = (v1.y - mean) * rstd * g1.y + b1v.y; y = LRELU(y); o8[5] = (_Float16)y;
        y = (v1.z - mean) * rstd * g1.z + b1v.z; y = LRELU(y); o8[6] = (_Float16)y;
        y = (v1.w - mean) * rstd * g1.w + b1v.w; y = LRELU(y); o8[7] = (_Float16)y;

        *(float4*)&a[(size_t)row * 512 + lane * 8] = *(const float4*)o8;
    }
}

// ---------------------------------------------------------------------------
// Main GEMM [schedule byte-identical to R12/R15].  FUSED=true adds grid.sync
// + per-block reduction of its own output chunk (cooperative launch only).
// ---------------------------------------------------------------------------
template <int NSPLIT, bool FUSED>
__global__ __launch_bounds__(256, 2) void gemm_kernel(
    const _Float16* __restrict__ A,   // [4096][512]
    const _Float16* __restrict__ Wt,  // [512][8192]
    const float* __restrict__ bfg,    // [4096][16]
    const float* __restrict__ bvec,   // [16][512]
    _Float16* __restrict__ pout,      // [NSPLIT][4096][512] f16
    float* __restrict__ outp)         // [4096][512] f32 (used when FUSED)
{
    constexpr int KTN = 16 / NSPLIT;   // 4 kt-groups per block
    constexpr int NT  = KTN * 8;       // 32 K-tiles of 64

    __shared__ _Float16 As[2][128 * 64];  // 32 KB
    __shared__ _Float16 Bs[2][128 * 64];  // 32 KB

    const int tid = threadIdx.x;
    const int bid = blockIdx.x;
    const int split = bid % NSPLIT;
    const int mn  = bid / NSPLIT;
    const int n0  = (mn & 3) * 128;
    const int bm0 = (mn >> 2) * 128;
    const int kt0 = split * KTN;

    const int lane = tid & 63, wid = tid >> 6;
    const int wm = wid >> 1, wn = wid & 1;   // 2x2 wave grid
    const int l16 = lane & 15, lg = lane >> 4;

    // per-lane A-row scales: row = bm0 + wm*64 + f*16 + l16
    _Float16 s16[KTN][4];
#pragma unroll
    for (int kt = 0; kt < KTN; ++kt)
#pragma unroll
        for (int f = 0; f < 4; ++f)
            s16[kt][f] = (_Float16)
                bfg[(size_t)(bm0 + wm * 64 + f * 16 + l16) * 16 + kt0 + kt];

    // staging: tile = 128x64 f16 = 1024 16B-chunks; round p: chunk = p*256+tid
    // -> row = p*32 + (tid>>3), col-chunk c = tid&7; source chunk = c^(row&7)
    const int brow = tid >> 3;
    const int swc  = (tid & 7) ^ (brow & 7);
    const _Float16* aAs = A  + (size_t)(bm0 + brow) * 512  + swc * 8;
    const _Float16* aBs = Wt + (size_t)(n0  + brow) * 8192 + swc * 8;

    auto STAGE = [&](int t, int buf) {   // full-tile stage (prologue only)
        const int ka = (t & 7) * 64;
        const size_t kb = (size_t)(kt0 + (t >> 3)) * 512 + ka;
        char* la = (char*)&As[buf][0] + tid * 16;
        char* lb = (char*)&Bs[buf][0] + tid * 16;
#pragma unroll
        for (int p = 0; p < 4; ++p) {
            GL16(aAs + (size_t)(p * 32) * 512 + ka, la + p * 4096);
            GL16(aBs + (size_t)(p * 32) * 8192 + kb, lb + p * 4096);
        }
    };

    // swizzled ds_read offsets (row&7 == l16&7 for all our rows)
    const int swr = l16 & 7;
    const int aRowByte = (wm * 64 + l16) * 128;
    const int bRowByte = (wn * 64 + l16) * 128;
    const int sw0 = ((0 + lg) ^ swr) << 4;   // kk = 0
    const int sw1 = ((4 + lg) ^ swr) << 4;   // kk = 1

    const f32x4 z4 = {0.f, 0.f, 0.f, 0.f};
    f32x4 acc[4][4];
#pragma unroll
    for (int f = 0; f < 4; ++f)
#pragma unroll
        for (int nf = 0; nf < 4; ++nf) acc[f][nf] = z4;

    // prologue: stage tiles 0,1; wait tile 0 (8 of 16 outstanding)
    STAGE(0, 0);
    STAGE(1, 1);
    asm volatile("s_waitcnt vmcnt(8)" ::: "memory");
    __builtin_amdgcn_s_barrier();
    __builtin_amdgcn_sched_barrier(0);

#pragma unroll
    for (int kt = 0; kt < KTN; ++kt) {
#pragma unroll 1
        for (int t2 = 0; t2 < 8; ++t2) {
            const int t = kt * 8 + t2;
            const int cur = t & 1;
            const char* Ab = (const char*)&As[cur][0];
            const char* Bb = (const char*)&Bs[cur][0];
            const int tt = t + 2;                 // tile being staged into buf cur
            const bool st = (tt < NT);
            char* sAd = (char*)&As[cur][0] + tid * 16;
            char* sBd = (char*)&Bs[cur][0] + tid * 16;
            const int ka = (tt & 7) * 64;
            const size_t kb = (size_t)(kt0 + (tt >> 3)) * 512 + ka;

            // ---- P0 reads: B all (8) + A f0,f1 (4)
            f16x8 bA0 = *(const f16x8*)(Bb + bRowByte + 0 * 2048 + sw0);
            f16x8 bA1 = *(const f16x8*)(Bb + bRowByte + 0 * 2048 + sw1);
            f16x8 bB0 = *(const f16x8*)(Bb + bRowByte + 1 * 2048 + sw0);
            f16x8 bB1 = *(const f16x8*)(Bb + bRowByte + 1 * 2048 + sw1);
            f16x8 bC0 = *(const f16x8*)(Bb + bRowByte + 2 * 2048 + sw0);
            f16x8 bC1 = *(const f16x8*)(Bb + bRowByte + 2 * 2048 + sw1);
            f16x8 bD0 = *(const f16x8*)(Bb + bRowByte + 3 * 2048 + sw0);
            f16x8 bD1 = *(const f16x8*)(Bb + bRowByte + 3 * 2048 + sw1);
            f16x8 a00 = *(const f16x8*)(Ab + aRowByte + 0 * 2048 + sw0);
            f16x8 a01 = *(const f16x8*)(Ab + aRowByte + 0 * 2048 + sw1);
            f16x8 a10 = *(const f16x8*)(Ab + aRowByte + 1 * 2048 + sw0);
            f16x8 a11 = *(const f16x8*)(Ab + aRowByte + 1 * 2048 + sw1);
            __builtin_amdgcn_s_barrier();

            // ---- C0: f0,f1 (16 MFMA)
            {
                const _Float16 s0 = s16[kt][0], s1 = s16[kt][1];
                a00 *= s0; a01 *= s0; a10 *= s1; a11 *= s1;
                __builtin_amdgcn_s_setprio(1);
                acc[0][0] = MFMA16(a00, bA0, acc[0][0]);
                acc[0][0] = MFMA16(a01, bA1, acc[0][0]);
                acc[0][1] = MFMA16(a00, bB0, acc[0][1]);
                acc[0][1] = MFMA16(a01, bB1, acc[0][1]);
                acc[0][2] = MFMA16(a00, bC0, acc[0][2]);
                acc[0][2] = MFMA16(a01, bC1, acc[0][2]);
                acc[0][3] = MFMA16(a00, bD0, acc[0][3]);
                acc[0][3] = MFMA16(a01, bD1, acc[0][3]);
                acc[1][0] = MFMA16(a10, bA0, acc[1][0]);
                acc[1][0] = MFMA16(a11, bA1, acc[1][0]);
                acc[1][1] = MFMA16(a10, bB0, acc[1][1]);
                acc[1][1] = MFMA16(a11, bB1, acc[1][1]);
                acc[1][2] = MFMA16(a10, bC0, acc[1][2]);
                acc[1][2] = MFMA16(a11, bC1, acc[1][2]);
                acc[1][3] = MFMA16(a10, bD0, acc[1][3]);
                acc[1][3] = MFMA16(a11, bD1, acc[1][3]);
                __builtin_amdgcn_s_setprio(0);
            }
            __builtin_amdgcn_s_barrier();

            // ---- P1 reads: A f2,f3; stage B r0-3 + A r0,r2 of tile t+2
            f16x8 a20 = *(const f16x8*)(Ab + aRowByte + 2 * 2048 + sw0);
            f16x8 a21 = *(const f16x8*)(Ab + aRowByte + 2 * 2048 + sw1);
            f16x8 a30 = *(const f16x8*)(Ab + aRowByte + 3 * 2048 + sw0);
            f16x8 a31 = *(const f16x8*)(Ab + aRowByte + 3 * 2048 + sw1);
            if (st) {
                GL16(aBs + (size_t)(0 * 32) * 8192 + kb, sBd + 0 * 4096);
                GL16(aBs + (size_t)(1 * 32) * 8192 + kb, sBd + 1 * 4096);
                GL16(aBs + (size_t)(2 * 32) * 8192 + kb, sBd + 2 * 4096);
                GL16(aBs + (size_t)(3 * 32) * 8192 + kb, sBd + 3 * 4096);
                GL16(aAs + (size_t)(0 * 32) * 512 + ka, sAd + 0 * 4096);
                GL16(aAs + (size_t)(2 * 32) * 512 + ka, sAd + 2 * 4096);
            }
            __builtin_amdgcn_s_barrier();

            // ---- C1: f2,f3 (16 MFMA)
            {
                const _Float16 s2 = s16[kt][2], s3 = s16[kt][3];
                a20 *= s2; a21 *= s2; a30 *= s3; a31 *= s3;
                __builtin_amdgcn_s_setprio(1);
                acc[2][0] = MFMA16(a20, bA0, acc[2][0]);
                acc[2][0] = MFMA16(a21, bA1, acc[2][0]);
                acc[2][1] = MFMA16(a20, bB0, acc[2][1]);
                acc[2][1] = MFMA16(a21, bB1, acc[2][1]);
                acc[2][2] = MFMA16(a20, bC0, acc[2][2]);
                acc[2][2] = MFMA16(a21, bC1, acc[2][2]);
                acc[2][3] = MFMA16(a20, bD0, acc[2][3]);
                acc[2][3] = MFMA16(a21, bD1, acc[2][3]);
                acc[3][0] = MFMA16(a30, bA0, acc[3][0]);
                acc[3][0] = MFMA16(a31, bA1, acc[3][0]);
                acc[3][1] = MFMA16(a30, bB0, acc[3][1]);
                acc[3][1] = MFMA16(a31, bB1, acc[3][1]);
                acc[3][2] = MFMA16(a30, bC0, acc[3][2]);
                acc[3][2] = MFMA16(a31, bC1, acc[3][2]);
                acc[3][3] = MFMA16(a30, bD0, acc[3][3]);
                acc[3][3] = MFMA16(a31, bD1, acc[3][3]);
                __builtin_amdgcn_s_setprio(0);
            }
            __builtin_amdgcn_s_barrier();

            // ---- tail: stage A r1,r3; counted vmcnt; tile-boundary fence
            if (st) {
                GL16(aAs + (size_t)(1 * 32) * 512 + ka, sAd + 1 * 4096);
                GL16(aAs + (size_t)(3 * 32) * 512 + ka, sAd + 3 * 4096);
                asm volatile("s_waitcnt vmcnt(8)" ::: "memory");
            } else {
                asm volatile("s_waitcnt vmcnt(0)" ::: "memory");
            }
            __builtin_amdgcn_s_barrier();
            __builtin_amdgcn_sched_barrier(0);
        }
    }

    // ---- epilogue: fold bf@bvec for this split's kt range (f32), store f16
    _Float16* op = pout + (size_t)split * (4096 * 512);
    const int colBase = n0 + wn * 64 + l16;
    float bvv[KTN][4];
#pragma unroll
    for (int kt = 0; kt < KTN; ++kt)
#pragma unroll
        for (int nf = 0; nf < 4; ++nf)
            bvv[kt][nf] = bvec[(kt0 + kt) * 512 + colBase + nf * 16];

#pragma unroll
    for (int f = 0; f < 4; ++f)
#pragma unroll
        for (int j = 0; j < 4; ++j) {
            const int grow = bm0 + wm * 64 + f * 16 + lg * 4 + j;
            const float* bfr = &bfg[(size_t)grow * 16 + kt0];
            float bfl[KTN];
#pragma unroll
            for (int kt = 0; kt < KTN; ++kt) bfl[kt] = bfr[kt];
            _Float16* orow = op + (size_t)grow * 512 + colBase;
#pragma unroll
            for (int nf = 0; nf < 4; ++nf) {
                float v = acc[f][nf][j];
#pragma unroll
                for (int kt = 0; kt < KTN; ++kt) v += bfl[kt] * bvv[kt][nf];
                orow[nf * 16] = (_Float16)v;
            }
        }

    if constexpr (FUSED) {
        // grid-wide barrier (cooperative launch): all partials visible after.
        cooperative_groups::this_grid().sync();
        // each block reduces its own 4096-f32 chunk: 2 chunks of 8 per thread
#pragma unroll
        for (int rep = 0; rep < 2; ++rep) {
            size_t i   = (size_t)bid * 512 + rep * 256 + tid;  // 8-elem chunk
            size_t off = i * 8;
            float s[8] = {0.f, 0.f, 0.f, 0.f, 0.f, 0.f, 0.f, 0.f};
#pragma unroll
            for (int sp = 0; sp < NSPLIT; ++sp) {
                f16x8 v = *(const f16x8*)&pout[(size_t)sp * 2097152 + off];
#pragma unroll
                for (int u = 0; u < 8; ++u) s[u] += (float)v[u];
            }
            float4 o0 = {s[0], s[1], s[2], s[3]};
            float4 o1 = {s[4], s[5], s[6], s[7]};
            *(float4*)&outp[off]     = o0;
            *(float4*)&outp[off + 4] = o1;
        }
    }
}

// ---------------------------------------------------------------------------
// Fallback reduce (non-cooperative path only).
// ---------------------------------------------------------------------------
__global__ __launch_bounds__(256) void reduce_kernel(const _Float16* __restrict__ p,
                                                     float* __restrict__ out,
                                                     int nsplit)
{
    size_t i   = (size_t)blockIdx.x * 256 + threadIdx.x;  // 8-elem chunk index
    size_t off = i * 8;
    float s[8] = {0.f, 0.f, 0.f, 0.f, 0.f, 0.f, 0.f, 0.f};
    for (int sp = 0; sp < nsplit; ++sp) {
        f16x8 v = *(const f16x8*)&p[(size_t)sp * 2097152 + off];
#pragma unroll
        for (int u = 0; u < 8; ++u) s[u] += (float)v[u];
    }
    float4 o0 = {s[0], s[1], s[2], s[3]};
    float4 o1 = {s[4], s[5], s[6], s[7]};
    *(float4*)&out[off]     = o0;
    *(float4*)&out[off + 4] = o1;
}

// ---------------------------------------------------------------------------
extern "C" void kernel_launch(void* const* d_in, const int* in_sizes, int n_in,
                              void* d_out, int out_size, void* d_ws, size_t ws_size,
                              hipStream_t stream)
{
    const float* x    = (const float*)d_in[0];
    const float* c    = (const float*)d_in[1];
    const float* gam  = (const float*)d_in[2];
    const float* bet  = (const float*)d_in[3];
    const float* w1   = (const float*)d_in[4];
    const float* b1   = (const float*)d_in[5];
    const float* wr   = (const float*)d_in[6];
    const float* br   = (const float*)d_in[7];
    const float* w2   = (const float*)d_in[8];
    const float* b2   = (const float*)d_in[9];
    const float* W    = (const float*)d_in[10];
    const float* bvec = (const float*)d_in[11];
    float* out = (float*)d_out;

    // f16 partials: 4 splits x 4 MB = 16 MB; + Wt 8 + a 4 + bf 0.25 = 28.25 MB
    const int nsplit = 4;
    const size_t partBytes = (size_t)nsplit * 4096 * 512 * sizeof(_Float16);

    char* ws = (char*)d_ws;
    _Float16* part = (_Float16*)ws;
    _Float16* Wt   = (_Float16*)(ws + partBytes);
    _Float16* af   = (_Float16*)(ws + partBytes + (8u << 20));
    float*    bf   = (float*)(ws + partBytes + (12u << 20));

    prep_kernel<<<dim3(2560), dim3(256), 0, stream>>>(
        x, gam, bet, af, c, w1, b1, wr, br, w2, b2, bf, W, Wt);

    // fused gemm+reduce via cooperative launch (512 blocks = exactly 2/CU);
    // fall back to the proven non-fused pair if rejected.
    const _Float16* afc = af;
    const _Float16* Wtc = Wt;
    const float*    bfc = bf;
    const float*    bvc = bvec;
    _Float16*       ptc = part;
    float*          otc = out;
    void* kargs[] = {(void*)&afc, (void*)&Wtc, (void*)&bfc,
                     (void*)&bvc, (void*)&ptc, (void*)&otc};
    hipError_t err = hipLaunchCooperativeKernel(
        reinterpret_cast<void*>(&gemm_kernel<4, true>),
        dim3(512), dim3(256), kargs, 0, stream);
    if (err != hipSuccess) {
        gemm_kernel<4, false><<<dim3(512), dim3(256), 0, stream>>>(
            af, Wt, bf, bvec, part, out);
        reduce_kernel<<<dim3(1024), dim3(256), 0, stream>>>(part, out, nsplit);
    }
}

// Round 17
// 82.628 us; speedup vs baseline: 2.0231x; 2.0231x over previous
//
#include <hip/hip_runtime.h>

// ConditionalPreactivation: out = Z @ Wflat + bf @ bvec,
//   Z[b, k*512+i] = bf[b,k] * a[b,i],  a = lrelu(LN(x)),  bf = basis(c).
// FINAL (= round 12, measured best 83.2 us):
// 128x128 deep-pipelined GEMM at 2 independent blocks/CU (2-deep dbuf,
// counted vmcnt(8), raw barriers, T2 both-sides swizzle, setprio),
// 4 waves/block, NSPLIT=4 -> grid 512.  bf applied in-register on A-frags;
// bf@bvec folded in the gemm epilogue; f16 partials; 4-way reduce.
// B=4096, DIN=512, DOUT=512, DC=64, K=16, DB=256.

#define LRELU(v) ((v) >= 0.f ? (v) : 0.01f * (v))

typedef _Float16 f16x8 __attribute__((ext_vector_type(8)));
typedef float f32x4 __attribute__((ext_vector_type(4)));

#define GL16(gp, lp) __builtin_amdgcn_global_load_lds(                      \
    (const __attribute__((address_space(1))) void*)(gp),                    \
    (__attribute__((address_space(3))) void*)(lp), 16, 0, 0)

#define MFMA16(a, b, c) __builtin_amdgcn_mfma_f32_16x16x32_f16((a), (b), (c), 0, 0, 0)

// ---------------------------------------------------------------------------
// Fused prep: blocks [0,512)      basis functions -> bf f32  (8 rows/block)
//             blocks [512,1536)   W f32 -> Wt f16 transposed [o][k*512+i]
//             blocks [1536,2560)  LayerNorm+lrelu -> a f16
// ---------------------------------------------------------------------------
__global__ __launch_bounds__(256) void prep_kernel(
    const float* __restrict__ x, const float* __restrict__ gam,
    const float* __restrict__ bet, _Float16* __restrict__ a,
    const float* __restrict__ c, const float* __restrict__ w1,
    const float* __restrict__ b1, const float* __restrict__ wr,
    const float* __restrict__ br, const float* __restrict__ w2,
    const float* __restrict__ b2, float* __restrict__ bfo,
    const float* __restrict__ W, _Float16* __restrict__ Wt)
{
    __shared__ __align__(16) char smem[18432];
    int tid = threadIdx.x;
    int blk = blockIdx.x;

    if (blk < 512) {
        float* c_l  = (float*)smem;             // 8*64  = 2 KB
        float* lr_l = (float*)(smem + 2048);    // 8*256 = 8 KB
        float* h_l  = (float*)(smem + 10240);   // 8*256 = 8 KB
        int b0 = blk * 8;

        for (int i = tid; i < 8 * 64; i += 256) c_l[i] = c[(size_t)b0 * 64 + i];

        float w1c[64];
#pragma unroll
        for (int u = 0; u < 64; ++u) w1c[u] = w1[u * 256 + tid];
        float b1s = b1[tid];
        __syncthreads();

        float h1[8];
#pragma unroll
        for (int r = 0; r < 8; ++r) h1[r] = b1s;
#pragma unroll
        for (int j4 = 0; j4 < 16; ++j4) {
#pragma unroll
            for (int r = 0; r < 8; ++r) {
                float4 cv = *(const float4*)&c_l[r * 64 + j4 * 4];
                h1[r] += cv.x * w1c[j4 * 4 + 0] + cv.y * w1c[j4 * 4 + 1] +
                         cv.z * w1c[j4 * 4 + 2] + cv.w * w1c[j4 * 4 + 3];
            }
        }
#pragma unroll
        for (int r = 0; r < 8; ++r) lr_l[r * 256 + tid] = LRELU(h1[r]);
        __syncthreads();

        float brv = br[tid];
        float h2[8];
#pragma unroll
        for (int r = 0; r < 8; ++r) h2[r] = h1[r] + brv;

#pragma unroll 1
        for (int jc = 0; jc < 8; ++jc) {
            float w8[32];
#pragma unroll
            for (int u = 0; u < 32; ++u) w8[u] = wr[(jc * 32 + u) * 256 + tid];
#pragma unroll
            for (int j4 = 0; j4 < 8; ++j4) {
#pragma unroll
                for (int r = 0; r < 8; ++r) {
                    float4 lv = *(const float4*)&lr_l[r * 256 + jc * 32 + j4 * 4];
                    h2[r] += lv.x * w8[j4 * 4 + 0] + lv.y * w8[j4 * 4 + 1] +
                             lv.z * w8[j4 * 4 + 2] + lv.w * w8[j4 * 4 + 3];
                }
            }
        }
#pragma unroll
        for (int r = 0; r < 8; ++r) h_l[r * 256 + tid] = LRELU(h2[r]);
        __syncthreads();

        if (tid < 128) {
            int r = tid >> 4, k = tid & 15;
            float s = b2[k];
#pragma unroll 1
            for (int qc = 0; qc < 8; ++qc) {
                float wv[32];
#pragma unroll
                for (int u = 0; u < 32; ++u) wv[u] = w2[(qc * 32 + u) * 16 + k];
#pragma unroll
                for (int q4 = 0; q4 < 8; ++q4) {
                    float4 hv = *(const float4*)&h_l[r * 256 + qc * 32 + q4 * 4];
                    s += hv.x * wv[q4 * 4 + 0] + hv.y * wv[q4 * 4 + 1] +
                         hv.z * wv[q4 * 4 + 2] + hv.w * wv[q4 * 4 + 3];
                }
            }
            bfo[(size_t)(b0 + r) * 16 + k] = s;
        }

    } else if (blk < 1536) {
        float* t = (float*)smem;  // 64*65*4 = 16.25 KB
        int bid = blk - 512;
        int k  = bid >> 6;
        int it = (bid >> 3) & 7;
        int ot = bid & 7;
        int i0 = it * 64, o0 = ot * 64;

        int rr = tid >> 4, c4 = (tid & 15) * 4;
#pragma unroll
        for (int p = 0; p < 4; ++p) {
            int r = p * 16 + rr;
            float4 v = *(const float4*)&W[((size_t)(k * 512 + i0 + r)) * 512 + o0 + c4];
            t[r * 65 + c4 + 0] = v.x;
            t[r * 65 + c4 + 1] = v.y;
            t[r * 65 + c4 + 2] = v.z;
            t[r * 65 + c4 + 3] = v.w;
        }
        __syncthreads();

        int ol = tid >> 2, c0 = (tid & 3) * 16;
        _Float16 hb[16] __attribute__((aligned(16)));
#pragma unroll
        for (int u = 0; u < 16; ++u) hb[u] = (_Float16)t[(c0 + u) * 65 + ol];
        _Float16* dst = &Wt[(size_t)(o0 + ol) * 8192 + k * 512 + i0 + c0];
        *(float4*)dst       = *(const float4*)&hb[0];
        *(float4*)(dst + 8) = *(const float4*)&hb[8];

    } else {
        int lane = tid & 63;
        int row  = (blk - 1536) * 4 + (tid >> 6);
        const float* xr = x + (size_t)row * 512 + lane * 8;
        float4 v0 = *(const float4*)xr;
        float4 v1 = *(const float4*)(xr + 4);

        float s = v0.x + v0.y + v0.z + v0.w + v1.x + v1.y + v1.z + v1.w;
#pragma unroll
        for (int m = 1; m < 64; m <<= 1) s += __shfl_xor(s, m);
        float mean = s * (1.f / 512.f);

        float d, s2 = 0.f;
        d = v0.x - mean; s2 += d * d;
        d = v0.y - mean; s2 += d * d;
        d = v0.z - mean; s2 += d * d;
        d = v0.w - mean; s2 += d * d;
        d = v1.x - mean; s2 += d * d;
        d = v1.y - mean; s2 += d * d;
        d = v1.z - mean; s2 += d * d;
        d = v1.w - mean; s2 += d * d;
#pragma unroll
        for (int m = 1; m < 64; m <<= 1) s2 += __shfl_xor(s2, m);
        float rstd = rsqrtf(s2 * (1.f / 512.f) + 1e-5f);

        float4 g0 = *(const float4*)&gam[lane * 8];
        float4 g1 = *(const float4*)&gam[lane * 8 + 4];
        float4 b0 = *(const float4*)&bet[lane * 8];
        float4 b1v = *(const float4*)&bet[lane * 8 + 4];

        _Float16 o8[8] __attribute__((aligned(16)));
        float y;
        y = (v0.x - mean) * rstd * g0.x + b0.x;  y = LRELU(y); o8[0] = (_Float16)y;
        y = (v0.y - mean) * rstd * g0.y + b0.y;  y = LRELU(y); o8[1] = (_Float16)y;
        y = (v0.z - mean) * rstd * g0.z + b0.z;  y = LRELU(y); o8[2] = (_Float16)y;
        y = (v0.w - mean) * rstd * g0.w + b0.w;  y = LRELU(y); o8[3] = (_Float16)y;
        y = (v1.x - mean) * rstd * g1.x + b1v.x; y = LRELU(y); o8[4] = (_Float16)y;
        y = (v1.y - mean) * rstd * g1.y + b1v.y; y = LRELU(y); o8[5] = (_Float16)y;
        y = (v1.z - mean) * rstd * g1.z + b1v.z; y = LRELU(y); o8[6] = (_Float16)y;
        y = (v1.w - mean) * rstd * g1.w + b1v.w; y = LRELU(y); o8[7] = (_Float16)y;

        *(float4*)&a[(size_t)row * 512 + lane * 8] = *(const float4*)o8;
    }
}

// ---------------------------------------------------------------------------
// Main GEMM: 128x128 tile, BK=64, 4 waves (2x2), 2-deep LDS double buffer,
// counted vmcnt(8), raw s_barriers, T2 both-sides swizzle, setprio.
// 2 independent blocks/CU (64 KB LDS each).  kt-outer.  Epilogue folds
// bf@bvec (f32) and stores f16 partials.
// ---------------------------------------------------------------------------
template <int NSPLIT>
__global__ __launch_bounds__(256, 2) void gemm_kernel(
    const _Float16* __restrict__ A,   // [4096][512]
    const _Float16* __restrict__ Wt,  // [512][8192]
    const float* __restrict__ bfg,    // [4096][16]
    const float* __restrict__ bvec,   // [16][512]
    _Float16* __restrict__ pout)      // [NSPLIT][4096][512] f16
{
    constexpr int KTN = 16 / NSPLIT;   // 4 kt-groups per block
    constexpr int NT  = KTN * 8;       // 32 K-tiles of 64

    __shared__ _Float16 As[2][128 * 64];  // 32 KB
    __shared__ _Float16 Bs[2][128 * 64];  // 32 KB

    const int tid = threadIdx.x;
    const int bid = blockIdx.x;
    const int split = bid % NSPLIT;
    const int mn  = bid / NSPLIT;
    const int n0  = (mn & 3) * 128;
    const int bm0 = (mn >> 2) * 128;
    const int kt0 = split * KTN;

    const int lane = tid & 63, wid = tid >> 6;
    const int wm = wid >> 1, wn = wid & 1;   // 2x2 wave grid
    const int l16 = lane & 15, lg = lane >> 4;

    // per-lane A-row scales: row = bm0 + wm*64 + f*16 + l16
    _Float16 s16[KTN][4];
#pragma unroll
    for (int kt = 0; kt < KTN; ++kt)
#pragma unroll
        for (int f = 0; f < 4; ++f)
            s16[kt][f] = (_Float16)
                bfg[(size_t)(bm0 + wm * 64 + f * 16 + l16) * 16 + kt0 + kt];

    // staging: tile = 128x64 f16 = 1024 16B-chunks; round p: chunk = p*256+tid
    // -> row = p*32 + (tid>>3), col-chunk c = tid&7; source chunk = c^(row&7)
    const int brow = tid >> 3;
    const int swc  = (tid & 7) ^ (brow & 7);
    const _Float16* aAs = A  + (size_t)(bm0 + brow) * 512  + swc * 8;
    const _Float16* aBs = Wt + (size_t)(n0  + brow) * 8192 + swc * 8;

    auto STAGE = [&](int t, int buf) {   // full-tile stage (prologue only)
        const int ka = (t & 7) * 64;
        const size_t kb = (size_t)(kt0 + (t >> 3)) * 512 + ka;
        char* la = (char*)&As[buf][0] + tid * 16;
        char* lb = (char*)&Bs[buf][0] + tid * 16;
#pragma unroll
        for (int p = 0; p < 4; ++p) {
            GL16(aAs + (size_t)(p * 32) * 512 + ka, la + p * 4096);
            GL16(aBs + (size_t)(p * 32) * 8192 + kb, lb + p * 4096);
        }
    };

    // swizzled ds_read offsets (row&7 == l16&7 for all our rows)
    const int swr = l16 & 7;
    const int aRowByte = (wm * 64 + l16) * 128;
    const int bRowByte = (wn * 64 + l16) * 128;
    const int sw0 = ((0 + lg) ^ swr) << 4;   // kk = 0
    const int sw1 = ((4 + lg) ^ swr) << 4;   // kk = 1

    const f32x4 z4 = {0.f, 0.f, 0.f, 0.f};
    f32x4 acc[4][4];
#pragma unroll
    for (int f = 0; f < 4; ++f)
#pragma unroll
        for (int nf = 0; nf < 4; ++nf) acc[f][nf] = z4;

    // prologue: stage tiles 0,1; wait tile 0 (8 of 16 outstanding)
    STAGE(0, 0);
    STAGE(1, 1);
    asm volatile("s_waitcnt vmcnt(8)" ::: "memory");
    __builtin_amdgcn_s_barrier();
    __builtin_amdgcn_sched_barrier(0);

#pragma unroll
    for (int kt = 0; kt < KTN; ++kt) {
#pragma unroll 1
        for (int t2 = 0; t2 < 8; ++t2) {
            const int t = kt * 8 + t2;
            const int cur = t & 1;
            const char* Ab = (const char*)&As[cur][0];
            const char* Bb = (const char*)&Bs[cur][0];
            const int tt = t + 2;                 // tile being staged into buf cur
            const bool st = (tt < NT);
            char* sAd = (char*)&As[cur][0] + tid * 16;
            char* sBd = (char*)&Bs[cur][0] + tid * 16;
            const int ka = (tt & 7) * 64;
            const size_t kb = (size_t)(kt0 + (tt >> 3)) * 512 + ka;

            // ---- P0 reads: B all (8) + A f0,f1 (4)
            f16x8 bA0 = *(const f16x8*)(Bb + bRowByte + 0 * 2048 + sw0);
            f16x8 bA1 = *(const f16x8*)(Bb + bRowByte + 0 * 2048 + sw1);
            f16x8 bB0 = *(const f16x8*)(Bb + bRowByte + 1 * 2048 + sw0);
            f16x8 bB1 = *(const f16x8*)(Bb + bRowByte + 1 * 2048 + sw1);
            f16x8 bC0 = *(const f16x8*)(Bb + bRowByte + 2 * 2048 + sw0);
            f16x8 bC1 = *(const f16x8*)(Bb + bRowByte + 2 * 2048 + sw1);
            f16x8 bD0 = *(const f16x8*)(Bb + bRowByte + 3 * 2048 + sw0);
            f16x8 bD1 = *(const f16x8*)(Bb + bRowByte + 3 * 2048 + sw1);
            f16x8 a00 = *(const f16x8*)(Ab + aRowByte + 0 * 2048 + sw0);
            f16x8 a01 = *(const f16x8*)(Ab + aRowByte + 0 * 2048 + sw1);
            f16x8 a10 = *(const f16x8*)(Ab + aRowByte + 1 * 2048 + sw0);
            f16x8 a11 = *(const f16x8*)(Ab + aRowByte + 1 * 2048 + sw1);
            __builtin_amdgcn_s_barrier();

            // ---- C0: f0,f1 (16 MFMA)
            {
                const _Float16 s0 = s16[kt][0], s1 = s16[kt][1];
                a00 *= s0; a01 *= s0; a10 *= s1; a11 *= s1;
                __builtin_amdgcn_s_setprio(1);
                acc[0][0] = MFMA16(a00, bA0, acc[0][0]);
                acc[0][0] = MFMA16(a01, bA1, acc[0][0]);
                acc[0][1] = MFMA16(a00, bB0, acc[0][1]);
                acc[0][1] = MFMA16(a01, bB1, acc[0][1]);
                acc[0][2] = MFMA16(a00, bC0, acc[0][2]);
                acc[0][2] = MFMA16(a01, bC1, acc[0][2]);
                acc[0][3] = MFMA16(a00, bD0, acc[0][3]);
                acc[0][3] = MFMA16(a01, bD1, acc[0][3]);
                acc[1][0] = MFMA16(a10, bA0, acc[1][0]);
                acc[1][0] = MFMA16(a11, bA1, acc[1][0]);
                acc[1][1] = MFMA16(a10, bB0, acc[1][1]);
                acc[1][1] = MFMA16(a11, bB1, acc[1][1]);
                acc[1][2] = MFMA16(a10, bC0, acc[1][2]);
                acc[1][2] = MFMA16(a11, bC1, acc[1][2]);
                acc[1][3] = MFMA16(a10, bD0, acc[1][3]);
                acc[1][3] = MFMA16(a11, bD1, acc[1][3]);
                __builtin_amdgcn_s_setprio(0);
            }
            __builtin_amdgcn_s_barrier();

            // ---- P1 reads: A f2,f3; stage B r0-3 + A r0,r2 of tile t+2
            f16x8 a20 = *(const f16x8*)(Ab + aRowByte + 2 * 2048 + sw0);
            f16x8 a21 = *(const f16x8*)(Ab + aRowByte + 2 * 2048 + sw1);
            f16x8 a30 = *(const f16x8*)(Ab + aRowByte + 3 * 2048 + sw0);
            f16x8 a31 = *(const f16x8*)(Ab + aRowByte + 3 * 2048 + sw1);
            if (st) {
                GL16(aBs + (size_t)(0 * 32) * 8192 + kb, sBd + 0 * 4096);
                GL16(aBs + (size_t)(1 * 32) * 8192 + kb, sBd + 1 * 4096);
                GL16(aBs + (size_t)(2 * 32) * 8192 + kb, sBd + 2 * 4096);
                GL16(aBs + (size_t)(3 * 32) * 8192 + kb, sBd + 3 * 4096);
                GL16(aAs + (size_t)(0 * 32) * 512 + ka, sAd + 0 * 4096);
                GL16(aAs + (size_t)(2 * 32) * 512 + ka, sAd + 2 * 4096);
            }
            __builtin_amdgcn_s_barrier();

            // ---- C1: f2,f3 (16 MFMA)
            {
                const _Float16 s2 = s16[kt][2], s3 = s16[kt][3];
                a20 *= s2; a21 *= s2; a30 *= s3; a31 *= s3;
                __builtin_amdgcn_s_setprio(1);
                acc[2][0] = MFMA16(a20, bA0, acc[2][0]);
                acc[2][0] = MFMA16(a21, bA1, acc[2][0]);
                acc[2][1] = MFMA16(a20, bB0, acc[2][1]);
                acc[2][1] = MFMA16(a21, bB1, acc[2][1]);
                acc[2][2] = MFMA16(a20, bC0, acc[2][2]);
                acc[2][2] = MFMA16(a21, bC1, acc[2][2]);
                acc[2][3] = MFMA16(a20, bD0, acc[2][3]);
                acc[2][3] = MFMA16(a21, bD1, acc[2][3]);
                acc[3][0] = MFMA16(a30, bA0, acc[3][0]);
                acc[3][0] = MFMA16(a31, bA1, acc[3][0]);
                acc[3][1] = MFMA16(a30, bB0, acc[3][1]);
                acc[3][1] = MFMA16(a31, bB1, acc[3][1]);
                acc[3][2] = MFMA16(a30, bC0, acc[3][2]);
                acc[3][2] = MFMA16(a31, bC1, acc[3][2]);
                acc[3][3] = MFMA16(a30, bD0, acc[3][3]);
                acc[3][3] = MFMA16(a31, bD1, acc[3][3]);
                __builtin_amdgcn_s_setprio(0);
            }
            __builtin_amdgcn_s_barrier();

            // ---- tail: stage A r1,r3; counted vmcnt; tile-boundary fence
            if (st) {
                GL16(aAs + (size_t)(1 * 32) * 512 + ka, sAd + 1 * 4096);
                GL16(aAs + (size_t)(3 * 32) * 512 + ka, sAd + 3 * 4096);
                asm volatile("s_waitcnt vmcnt(8)" ::: "memory");
            } else {
                asm volatile("s_waitcnt vmcnt(0)" ::: "memory");
            }
            __builtin_amdgcn_s_barrier();
            __builtin_amdgcn_sched_barrier(0);
        }
    }

    // ---- epilogue: fold bf@bvec for this split's kt range (f32), store f16
    _Float16* op = pout + (size_t)split * (4096 * 512);
    const int colBase = n0 + wn * 64 + l16;
    float bvv[KTN][4];
#pragma unroll
    for (int kt = 0; kt < KTN; ++kt)
#pragma unroll
        for (int nf = 0; nf < 4; ++nf)
            bvv[kt][nf] = bvec[(kt0 + kt) * 512 + colBase + nf * 16];

#pragma unroll
    for (int f = 0; f < 4; ++f)
#pragma unroll
        for (int j = 0; j < 4; ++j) {
            const int grow = bm0 + wm * 64 + f * 16 + lg * 4 + j;
            const float* bfr = &bfg[(size_t)grow * 16 + kt0];
            float bfl[KTN];
#pragma unroll
            for (int kt = 0; kt < KTN; ++kt) bfl[kt] = bfr[kt];
            _Float16* orow = op + (size_t)grow * 512 + colBase;
#pragma unroll
            for (int nf = 0; nf < 4; ++nf) {
                float v = acc[f][nf][j];
#pragma unroll
                for (int kt = 0; kt < KTN; ++kt) v += bfl[kt] * bvv[kt][nf];
                orow[nf * 16] = (_Float16)v;
            }
        }
}

// ---------------------------------------------------------------------------
// out = sum over splits of f16 partials.  8 f16 in / 8 f32 out per thread.
// ---------------------------------------------------------------------------
__global__ __launch_bounds__(256) void reduce_kernel(const _Float16* __restrict__ p,
                                                     float* __restrict__ out,
                                                     int nsplit)
{
    size_t i   = (size_t)blockIdx.x * 256 + threadIdx.x;  // 8-elem chunk index
    size_t off = i * 8;
    float s[8] = {0.f, 0.f, 0.f, 0.f, 0.f, 0.f, 0.f, 0.f};
    for (int sp = 0; sp < nsplit; ++sp) {
        f16x8 v = *(const f16x8*)&p[(size_t)sp * 2097152 + off];
#pragma unroll
        for (int u = 0; u < 8; ++u) s[u] += (float)v[u];
    }
    float4 o0 = {s[0], s[1], s[2], s[3]};
    float4 o1 = {s[4], s[5], s[6], s[7]};
    *(float4*)&out[off]     = o0;
    *(float4*)&out[off + 4] = o1;
}

// ---------------------------------------------------------------------------
extern "C" void kernel_launch(void* const* d_in, const int* in_sizes, int n_in,
                              void* d_out, int out_size, void* d_ws, size_t ws_size,
                              hipStream_t stream)
{
    const float* x    = (const float*)d_in[0];
    const float* c    = (const float*)d_in[1];
    const float* gam  = (const float*)d_in[2];
    const float* bet  = (const float*)d_in[3];
    const float* w1   = (const float*)d_in[4];
    const float* b1   = (const float*)d_in[5];
    const float* wr   = (const float*)d_in[6];
    const float* br   = (const float*)d_in[7];
    const float* w2   = (const float*)d_in[8];
    const float* b2   = (const float*)d_in[9];
    const float* W    = (const float*)d_in[10];
    const float* bvec = (const float*)d_in[11];
    float* out = (float*)d_out;

    // f16 partials: 4 splits x 4 MB = 16 MB; + Wt 8 + a 4 + bf 0.25 = 28.25 MB
    const int nsplit = 4;
    const size_t partBytes = (size_t)nsplit * 4096 * 512 * sizeof(_Float16);

    char* ws = (char*)d_ws;
    _Float16* part = (_Float16*)ws;
    _Float16* Wt   = (_Float16*)(ws + partBytes);
    _Float16* af   = (_Float16*)(ws + partBytes + (8u << 20));
    float*    bf   = (float*)(ws + partBytes + (12u << 20));

    prep_kernel<<<dim3(2560), dim3(256), 0, stream>>>(
        x, gam, bet, af, c, w1, b1, wr, br, w2, b2, bf, W, Wt);

    // 32 m-tiles * 4 n-tiles * 4 splits = 512 blocks (exactly 2 per CU)
    gemm_kernel<4><<<dim3(512), dim3(256), 0, stream>>>(af, Wt, bf, bvec, part);

    // 4096*512 / (256*8) = 1024 blocks
    reduce_kernel<<<dim3(1024), dim3(256), 0, stream>>>(part, out, nsplit);
}